// Round 11
// baseline (100.768 us; speedup 1.0000x reference)
//
#include <hip/hip_runtime.h>
#include <stdint.h>

// LIF SNN: cur = X @ W^T then LIF scan. T=256,B=64,F=1024 -> M=16384,N=K=1024.
// EXACT integer GEMM: W quantized at 2^-35 -> 4 signed i8 limbs,
// mfma_i32_32x32x32_i8 (exact i32 acc), fp64 limb combine (exact), one f32
// rounding -> decision-identical to exact fp64 (absmax 0.0, rounds 1-10).
//
// Round 11 = r10 frame + T4 (counted vmcnt, stages never drained) + T5
// (setprio around mfma cluster):
//  - B triple-buffered (3x16KB LDS). stage(c+2) issued at END of chunk c ->
//    stages are always the NEWEST outstanding VMEM; `s_waitcnt vmcnt(2)` +
//    raw s_barrier retires stage(c+1) (FIFO oldest-first) while stage(c+2)
//    and the A-ring stay in flight ACROSS the barrier (no vmcnt(0) drain).
//  - sched_barrier(0) pins the stage/wait block ordering.
//  - A global->reg prefetch depth 2 (a0/a1/a2 rotate, static).
//  - setprio(1) around each 4-mfma cluster; waves free-run within a chunk.

#define T_STEPS 256
#define M_DIM 16384
#define N_DIM 1024
#define K_DIM 1024
#define PLANE 65536   // B*F

typedef int v4i  __attribute__((ext_vector_type(4)));
typedef int v16i __attribute__((ext_vector_type(16)));
typedef unsigned int u32;
typedef unsigned long long u64;

// ws layouts
#define AB_BYTES   (M_DIM * K_DIM)                  // 16 MB A fragment bytes
#define AB_LIMB    AB_BYTES                         // B fragments at +16MB
#define WS_AB      (AB_BYTES + 4 * (1 << 20))       // 20 MB
#define MT_BITS    (M_DIM * 128)                    // 2 MB bit matrix
#define WS_MT      (MT_BITS + 4 * (1 << 20))        // 6 MB (mid tier)

__device__ __forceinline__ void gload_lds16(const void* g, void* l) {
    __builtin_amdgcn_global_load_lds(
        (const __attribute__((address_space(1))) u32*)g,
        (__attribute__((address_space(3))) u32*)l, 16, 0, 0);
}

// ------- prep: X (0/1 f32) -> A fragments [g 0..511][ks 0..31][lane][16B] ---
__global__ __launch_bounds__(256) void prep_bytes_f(const float* __restrict__ X,
                                                    uint4* __restrict__ af) {
    const int gid  = blockIdx.x * 256 + threadIdx.x;  // 0..1048575
    const int lane = gid & 63;
    const int fs   = gid >> 6;                        // g*32 + ks
    const int m    = (fs >> 5) * 32 + (lane & 31);
    const int k    = (fs & 31) * 32 + (lane >> 5) * 16;
    const float4* src = reinterpret_cast<const float4*>(X + (size_t)m * K_DIM + k);
    uint4 r;
    u32* pr = &r.x;
    #pragma unroll
    for (int q = 0; q < 4; ++q) {
        const float4 f = src[q];
        pr[q] = (f.x != 0.f ? 1u : 0u) | (f.y != 0.f ? 0x100u : 0u) |
                (f.z != 0.f ? 0x10000u : 0u) | (f.w != 0.f ? 0x1000000u : 0u);
    }
    af[gid] = r;
}

// ------- prep: W -> B limb fragments [c 0..31][ks 0..31][lb 0..3][lane][16B] -
__global__ __launch_bounds__(256) void prep_limbs_f(const float* __restrict__ W,
                                                    char* __restrict__ bf) {
    const int gid  = blockIdx.x * 256 + threadIdx.x;  // 0..65535
    const int lane = gid & 63;
    const int fs   = gid >> 6;                        // c*32 + ks
    const int n    = (fs >> 5) * 32 + (lane & 31);
    const int k    = (fs & 31) * 32 + (lane >> 5) * 16;
    const float* src = W + (size_t)n * K_DIM + k;
    u32 w0[4] = {}, w1[4] = {}, w2[4] = {}, w3[4] = {};
    #pragma unroll
    for (int e = 0; e < 16; ++e) {
        const double d = (double)src[e] * 34359738368.0;  // * 2^35, exact
        long long kq = llrint(d);                         // |kq| <= 2^30
        const int8_t l0 = (int8_t)kq; kq = (kq - l0) >> 8;  // exact digits
        const int8_t l1 = (int8_t)kq; kq = (kq - l1) >> 8;
        const int8_t l2 = (int8_t)kq; kq = (kq - l2) >> 8;
        const int8_t l3 = (int8_t)kq;
        const int sh = (e & 3) * 8, wd = e >> 2;
        w0[wd] |= ((u32)(uint8_t)l0) << sh;
        w1[wd] |= ((u32)(uint8_t)l1) << sh;
        w2[wd] |= ((u32)(uint8_t)l2) << sh;
        w3[wd] |= ((u32)(uint8_t)l3) << sh;
    }
    char* base = bf + (size_t)fs * 4096 + lane * 16;
    *(uint4*)(base)        = make_uint4(w0[0], w0[1], w0[2], w0[3]);
    *(uint4*)(base + 1024) = make_uint4(w1[0], w1[1], w1[2], w1[3]);
    *(uint4*)(base + 2048) = make_uint4(w2[0], w2[1], w2[2], w2[3]);
    *(uint4*)(base + 3072) = make_uint4(w3[0], w3[1], w3[2], w3[3]);
}

// ---------------- i8 MFMA GEMM: T4 counted-vmcnt pipeline ------------------
// Grid 2048 (1D); XCD swizzle L%8 -> bm stripe. Block 512 thr = 8 waves,
// tile 256m x 32n; wave w owns m-tile g = bm*8 + w. Chunk = 128k. LDS: B
// triple buffer [3][16KB]; frag id = ks*4+lb, lane-linear. Per wave per ks:
// 1 A gload (depth-2 ring) + 4 ds_read_b128 + 4 mfma (setprio-wrapped).
// One counted-vmcnt barrier per chunk; stages stay in flight across it.
__global__ __launch_bounds__(512, 4) void gemm_i8_t4(
    const char* __restrict__ af, const char* __restrict__ bf,
    float* __restrict__ out) {
    __shared__ __align__(16) char lds[3][16384];   // 48 KB

    const int tid  = threadIdx.x;
    const int lane = tid & 63;
    const int w    = tid >> 6;        // 0..7
    const int l31  = lane & 31;
    const int lh   = lane >> 5;

    const int L   = blockIdx.x;       // 0..2047
    const int xcd = L & 7;
    const int j   = L >> 3;           // 0..255
    const int bm  = xcd * 8 + (j & 7);  // XCD owns an 8-wide bm stripe
    const int bn  = j >> 3;             // 0..31

    v16i acc[4] = {};                 // [limb]

    // B panel base; wave w stages frag ids {2w, 2w+1} per chunk (lane-linear)
    const char* gB = bf + (size_t)bn * 131072 + (size_t)(2 * w) * 1024 + lane * 16;
    const int   lB = (2 * w) * 1024 + lane * 16;

    // A fragment source (lane-linear): m-tile g = bm*8 + w
    const char* gA = af + (size_t)(bm * 8 + w) * 32768 + lane * 16;

    // ---- prologue: stage chunks 0,1; A ring depth 2; wait stage(0) only ----
    gload_lds16(gB,                 (char*)lds[0] + lB);
    gload_lds16(gB + 1024,          (char*)lds[0] + lB + 1024);
    gload_lds16(gB + 16384,         (char*)lds[1] + lB);
    gload_lds16(gB + 16384 + 1024,  (char*)lds[1] + lB + 1024);
    v4i a0 = *(const v4i*)(gA);
    v4i a1 = *(const v4i*)(gA + 1024);
    v4i a2 = a1;
    __builtin_amdgcn_sched_barrier(0);
    // FIFO: [s0:2][s1:2][A:2] -> vmcnt(4) retires s0, keeps s1 + A in flight
    asm volatile("s_waitcnt vmcnt(4)" ::: "memory");
    __builtin_amdgcn_s_barrier();
    __builtin_amdgcn_sched_barrier(0);

    #pragma unroll
    for (int c = 0; c < 8; ++c) {     // 8 chunks of 128 k
        const char* rb = (const char*)lds[c % 3];
        #pragma unroll
        for (int ks = 0; ks < 4; ++ks) {
            const int kg = c * 4 + ks;
            if (kg + 2 < 32) a2 = *(const v4i*)(gA + (kg + 2) * 1024);
            __builtin_amdgcn_s_setprio(1);
            #pragma unroll
            for (int lb = 0; lb < 4; ++lb) {
                const v4i b = *(const v4i*)(rb + (ks * 4 + lb) * 1024 + lane * 16);
                acc[lb] = __builtin_amdgcn_mfma_i32_32x32x32_i8(a0, b, acc[lb], 0, 0, 0);
            }
            __builtin_amdgcn_s_setprio(0);
            a0 = a1; a1 = a2;         // rotate A ring (static)
        }
        if (c < 7) {
            __builtin_amdgcn_sched_barrier(0);
            if (c + 2 < 8) {          // stage chunk c+2 LAST (newest VMEM ops)
                char* wb2 = (char*)lds[(c + 2) % 3];
                gload_lds16(gB + (size_t)(c + 2) * 16384,        wb2 + lB);
                gload_lds16(gB + (size_t)(c + 2) * 16384 + 1024, wb2 + lB + 1024);
            }
            __builtin_amdgcn_sched_barrier(0);
            // retire everything older than the 2 newest (= stage(c+2));
            // guarantees stage(c+1) landed; keeps stage(c+2)+ring in flight
            asm volatile("s_waitcnt vmcnt(2)" ::: "memory");
            __builtin_amdgcn_s_barrier();
            __builtin_amdgcn_sched_barrier(0);
        }
    }

    // epilogue: combine limbs in fp64 (exact), one f32 rounding, store
    const int n = bn * 32 + l31;
    #pragma unroll
    for (int r = 0; r < 16; ++r) {
        const double s = (double)acc[0][r] + 256.0 * (double)acc[1][r] +
                         65536.0 * (double)acc[2][r] +
                         16777216.0 * (double)acc[3][r];
        const float cur = (float)(s * 2.9103830456733704e-11);  // * 2^-35
        const int row = (r & 3) + 8 * (r >> 2) + 4 * lh;
        const int m = (bm * 8 + w) * 32 + row;
        out[(size_t)m * N_DIM + n] = cur;
    }
}

// ======== mid tier (round-4 proven): bit-matrix A, in-register expand ======
__device__ __forceinline__ v4i expand16(u32 sb) {
    v4i r;
    #pragma unroll
    for (int q = 0; q < 4; ++q) {
        const u32 x = (sb >> (4 * q)) & 0xFu;
        r[q] = (int)((x * 0x00204081u) & 0x01010101u);
    }
    return r;
}

__global__ __launch_bounds__(256) void prep_bits(const float* __restrict__ X,
                                                 u64* __restrict__ bits) {
    const int gid = blockIdx.x * 256 + threadIdx.x;
    const float x = X[gid];
    const u64 m = __ballot(x != 0.0f);
    if ((threadIdx.x & 63) == 0) bits[gid >> 6] = m;
}

__global__ __launch_bounds__(256) void prep_limbs(const float* __restrict__ W,
                                                  char* __restrict__ limbs) {
    const int gid = blockIdx.x * 256 + threadIdx.x;   // 0..2^20-1
    const double d = (double)W[gid] * 34359738368.0;
    long long k = llrint(d);
    const int8_t l0 = (int8_t)k; k = (k - l0) >> 8;
    const int8_t l1 = (int8_t)k; k = (k - l1) >> 8;
    const int8_t l2 = (int8_t)k; k = (k - l2) >> 8;
    const int8_t l3 = (int8_t)k;
    limbs[gid]                 = (char)l0;
    limbs[gid + (1 << 20)]     = (char)l1;
    limbs[gid + 2 * (1 << 20)] = (char)l2;
    limbs[gid + 3 * (1 << 20)] = (char)l3;
}

__global__ __launch_bounds__(256, 2) void gemm_i8_reg2(
    const u64* __restrict__ bits, const char* __restrict__ limbs,
    float* __restrict__ out) {
    __shared__ __align__(16) char lds[2][32768];
    const int tid  = threadIdx.x;
    const int lane = tid & 63;
    const int w    = tid >> 6;
    const int l31  = lane & 31;
    const int lh   = lane >> 5;
    const int bn   = blockIdx.x;
    const int bm   = blockIdx.y;
    v16i acc[2][4] = {};
    const char* gB[8];
    #pragma unroll
    for (int j = 0; j < 8; ++j) {
        const int id = w * 8 + j;
        const int lb = id & 3, ks32 = id >> 2;
        gB[j] = limbs + (size_t)lb * (1 << 20) +
                (size_t)(bn * 32 + l31) * 1024 + (size_t)(ks32 * 32 + lh * 16);
    }
    const int ldsbase = w * 8192 + lane * 16;
    const u64* aRow0 = bits + (size_t)(bm * 256 + w * 64 + l31) * 16;
    const u64* aRow1 = aRow0 + 32 * 16;
    u64 aw0[4], aw1[4], an0[4], an1[4];
    #pragma unroll
    for (int j = 0; j < 8; ++j) gload_lds16(gB[j], lds[0] + ldsbase + j * 1024);
    #pragma unroll
    for (int q = 0; q < 4; ++q) { aw0[q] = aRow0[q]; aw1[q] = aRow1[q]; }
    __syncthreads();
    char* rb = lds[0];
    char* wb = lds[1];
    for (int c = 0; c < 4; ++c) {
        if (c < 3) {
            #pragma unroll
            for (int j = 0; j < 8; ++j)
                gload_lds16(gB[j] + (c + 1) * 256, wb + ldsbase + j * 1024);
            #pragma unroll
            for (int q = 0; q < 4; ++q) {
                an0[q] = aRow0[(c + 1) * 4 + q];
                an1[q] = aRow1[(c + 1) * 4 + q];
            }
        }
        #pragma unroll
        for (int ks = 0; ks < 8; ++ks) {
            const int sh = (ks & 1) * 32 + lh * 16;
            const v4i a0 = expand16((u32)(aw0[ks >> 1] >> sh) & 0xffffu);
            const v4i a1 = expand16((u32)(aw1[ks >> 1] >> sh) & 0xffffu);
            #pragma unroll
            for (int lb = 0; lb < 4; ++lb) {
                const v4i b = *(const v4i*)(rb + (ks * 4 + lb) * 1024 + lane * 16);
                acc[0][lb] = __builtin_amdgcn_mfma_i32_32x32x32_i8(a0, b, acc[0][lb], 0, 0, 0);
                acc[1][lb] = __builtin_amdgcn_mfma_i32_32x32x32_i8(a1, b, acc[1][lb], 0, 0, 0);
            }
        }
        __syncthreads();
        char* t2 = rb; rb = wb; wb = t2;
        #pragma unroll
        for (int q = 0; q < 4; ++q) { aw0[q] = an0[q]; aw1[q] = an1[q]; }
    }
    const int n = bn * 32 + l31;
    #pragma unroll
    for (int i = 0; i < 2; ++i) {
        #pragma unroll
        for (int r = 0; r < 16; ++r) {
            const double s = (double)acc[i][0][r] + 256.0 * (double)acc[i][1][r] +
                             65536.0 * (double)acc[i][2][r] +
                             16777216.0 * (double)acc[i][3][r];
            const float cur = (float)(s * 2.9103830456733704e-11);
            const int row = (r & 3) + 8 * (r >> 2) + 4 * lh;
            const int m = bm * 256 + w * 64 + i * 32 + row;
            out[(size_t)m * N_DIM + n] = cur;
        }
    }
}

// ---------------- LIF scan, fp64 state, depth-16 prefetch ring -------------
__global__ __launch_bounds__(256) void lif_scan4(float* __restrict__ buf) {
    const int gid = blockIdx.x * 256 + threadIdx.x;   // 0..65535
    float c[16];
    #pragma unroll
    for (int q = 0; q < 16; ++q) c[q] = buf[(size_t)q * PLANE + gid];
    double v = 0.0;
    for (int t = 0; t < T_STEPS; t += 16) {
        #pragma unroll
        for (int q = 0; q < 16; ++q) {
            const double cd = (double)c[q];
            v = v + (cd - v) * 0.5;
            const bool s = (v >= 1.0);
            buf[(size_t)(t + q) * PLANE + gid] = s ? 1.0f : 0.0f;
            v = s ? 0.0 : v;
            const int tn = t + q + 16;
            if (tn < T_STEPS) c[q] = buf[(size_t)tn * PLANE + gid];
        }
    }
}

// ---------------- fallback: round-1 fp64 GEMM (proven) ---------------------
__global__ __launch_bounds__(256) void lif_gemm_fp64(
    const float* __restrict__ X, const float* __restrict__ W,
    float* __restrict__ out) {
    __shared__ float As[64][68];
    __shared__ float Bs[64][68];
    const int tid = threadIdx.x;
    const int bn = blockIdx.x, bm = blockIdx.y;
    const int tn4 = tid & 15, tm4 = tid >> 4;
    double acc[4][4] = {};
    const int lrow = tid >> 2, lc4 = tid & 3;
    const float* Abase = X + (size_t)(bm * 64 + lrow) * K_DIM;
    const float* Bbase = W + (size_t)(bn * 64 + lrow) * K_DIM;
    for (int k0 = 0; k0 < K_DIM; k0 += 64) {
        #pragma unroll
        for (int j = 0; j < 4; ++j) {
            const int c = lc4 + 4 * j;
            float4 a = *reinterpret_cast<const float4*>(Abase + k0 + 4 * c);
            float4 b = *reinterpret_cast<const float4*>(Bbase + k0 + 4 * c);
            As[4*c+0][lrow] = a.x; As[4*c+1][lrow] = a.y;
            As[4*c+2][lrow] = a.z; As[4*c+3][lrow] = a.w;
            Bs[4*c+0][lrow] = b.x; Bs[4*c+1][lrow] = b.y;
            Bs[4*c+2][lrow] = b.z; Bs[4*c+3][lrow] = b.w;
        }
        __syncthreads();
        #pragma unroll 8
        for (int k = 0; k < 64; ++k) {
            float4 a4 = *reinterpret_cast<const float4*>(&As[k][tm4 * 4]);
            float4 b4 = *reinterpret_cast<const float4*>(&Bs[k][tn4 * 4]);
            const double ad[4] = {(double)a4.x, (double)a4.y, (double)a4.z, (double)a4.w};
            const double bd[4] = {(double)b4.x, (double)b4.y, (double)b4.z, (double)b4.w};
            #pragma unroll
            for (int i = 0; i < 4; ++i)
                #pragma unroll
                for (int j = 0; j < 4; ++j)
                    acc[i][j] = fma(ad[i], bd[j], acc[i][j]);
        }
        __syncthreads();
    }
    #pragma unroll
    for (int i = 0; i < 4; ++i) {
        const int m = bm * 64 + tm4 * 4 + i;
        float4 o;
        o.x = (float)acc[i][0]; o.y = (float)acc[i][1];
        o.z = (float)acc[i][2]; o.w = (float)acc[i][3];
        *reinterpret_cast<float4*>(out + (size_t)m * N_DIM + bn * 64 + tn4 * 4) = o;
    }
}

extern "C" void kernel_launch(void* const* d_in, const int* in_sizes, int n_in,
                              void* d_out, int out_size, void* d_ws, size_t ws_size,
                              hipStream_t stream) {
    const float* X = (const float*)d_in[0];
    const float* W = (const float*)d_in[1];
    float* out = (float*)d_out;
    char* ws = (char*)d_ws;

    if (ws_size >= (size_t)WS_AB) {
        char* afrag = ws;
        char* bfrag = ws + AB_LIMB;
        prep_bytes_f<<<M_DIM * K_DIM / (256 * 16), 256, 0, stream>>>(X, (uint4*)afrag);
        prep_limbs_f<<<N_DIM * K_DIM / (256 * 16), 256, 0, stream>>>(W, bfrag);
        gemm_i8_t4<<<2048, 512, 0, stream>>>(afrag, bfrag, out);
    } else if (ws_size >= (size_t)WS_MT) {
        u64* bits = (u64*)ws;
        char* limbs = ws + MT_BITS;
        prep_bits<<<M_DIM * K_DIM / 256, 256, 0, stream>>>(X, bits);
        prep_limbs<<<N_DIM * K_DIM / 256, 256, 0, stream>>>(W, limbs);
        dim3 grid(N_DIM / 32, M_DIM / 256);
        gemm_i8_reg2<<<grid, 256, 0, stream>>>(bits, limbs, out);
    } else {
        dim3 grid(N_DIM / 64, M_DIM / 64);
        lif_gemm_fp64<<<grid, 256, 0, stream>>>(X, W, out);
        lif_scan4<<<PLANE / 256, 256, 0, stream>>>(out);
        return;
    }
    lif_scan4<<<PLANE / 256, 256, 0, stream>>>(out);
}

// Round 12
// 92.791 us; speedup vs baseline: 1.0860x; 1.0860x over previous
//
#include <hip/hip_runtime.h>
#include <stdint.h>

// LIF SNN: cur = X @ W^T then LIF scan. T=256,B=64,F=1024 -> M=16384,N=K=1024.
// Integer GEMM on i8 MFMA. Round 12: THREE limbs at scale 2^-27 (was 4 at
// 2^-35). k = rint(W*2^27), |k| <= 2^22, 3 balanced i8 digits. Per-element
// quantization error <= 2^-28 -> per-dot error ~5e-8 typical, far below the
// inferred >=1e-6 decision margins (np-f32 ref's own ~3e-7 error produced
// ZERO flips vs exact across 11 rounds). i32 mfma acc exact; fp64 combine
// exact; one f32 rounding. 25% fewer mfma + ds_read + stage bytes.
// Frame = r10 (proven): 512 thr / 8 waves / 32m-tile each, 4 waves/SIMD,
// fragment-major operands, LDS-B dbuf, A global->reg prefetch, XCD swizzle.

#define T_STEPS 256
#define M_DIM 16384
#define N_DIM 1024
#define K_DIM 1024
#define PLANE 65536   // B*F

typedef int v4i  __attribute__((ext_vector_type(4)));
typedef int v16i __attribute__((ext_vector_type(16)));
typedef unsigned int u32;
typedef unsigned long long u64;

// ws layouts
#define AB_BYTES   (M_DIM * K_DIM)                  // 16 MB A fragment bytes
#define AB_LIMB    AB_BYTES                         // B fragments at +16MB (3MB)
#define WS_AB      (AB_BYTES + 4 * (1 << 20))       // 20 MB budget (3MB used)
#define MT_BITS    (M_DIM * 128)                    // 2 MB bit matrix
#define WS_MT      (MT_BITS + 4 * (1 << 20))        // 6 MB (mid tier, 4-limb)

__device__ __forceinline__ void gload_lds16(const void* g, void* l) {
    __builtin_amdgcn_global_load_lds(
        (const __attribute__((address_space(1))) u32*)g,
        (__attribute__((address_space(3))) u32*)l, 16, 0, 0);
}

// ------- prep: X (0/1 f32) -> A fragments [g 0..511][ks 0..31][lane][16B] ---
__global__ __launch_bounds__(256) void prep_bytes_f(const float* __restrict__ X,
                                                    uint4* __restrict__ af) {
    const int gid  = blockIdx.x * 256 + threadIdx.x;  // 0..1048575
    const int lane = gid & 63;
    const int fs   = gid >> 6;                        // g*32 + ks
    const int m    = (fs >> 5) * 32 + (lane & 31);
    const int k    = (fs & 31) * 32 + (lane >> 5) * 16;
    const float4* src = reinterpret_cast<const float4*>(X + (size_t)m * K_DIM + k);
    uint4 r;
    u32* pr = &r.x;
    #pragma unroll
    for (int q = 0; q < 4; ++q) {
        const float4 f = src[q];
        pr[q] = (f.x != 0.f ? 1u : 0u) | (f.y != 0.f ? 0x100u : 0u) |
                (f.z != 0.f ? 0x10000u : 0u) | (f.w != 0.f ? 0x1000000u : 0u);
    }
    af[gid] = r;
}

// ---- prep: W -> B 3-limb fragments [c 0..31][ks 0..31][lb 0..2][lane][16B] -
// lane l holds limb lb of W[c*32 + (l&31)][ks*32 + (l>>5)*16 .. +16],
// k = rint(W*2^27), |k| <= 2^22, balanced base-256 digits (|l2| <= 64).
__global__ __launch_bounds__(256) void prep_limbs_f3(const float* __restrict__ W,
                                                     char* __restrict__ bf) {
    const int gid  = blockIdx.x * 256 + threadIdx.x;  // 0..65535
    const int lane = gid & 63;
    const int fs   = gid >> 6;                        // c*32 + ks
    const int n    = (fs >> 5) * 32 + (lane & 31);
    const int k    = (fs & 31) * 32 + (lane >> 5) * 16;
    const float* src = W + (size_t)n * K_DIM + k;
    u32 w0[4] = {}, w1[4] = {}, w2[4] = {};
    #pragma unroll
    for (int e = 0; e < 16; ++e) {
        const double d = (double)src[e] * 134217728.0;    // * 2^27, exact
        long long kq = llrint(d);                         // |kq| <= 2^22
        const int8_t l0 = (int8_t)kq; kq = (kq - l0) >> 8;  // balanced digits
        const int8_t l1 = (int8_t)kq; kq = (kq - l1) >> 8;
        const int8_t l2 = (int8_t)kq;                     // |l2| <= 64
        const int sh = (e & 3) * 8, wd = e >> 2;
        w0[wd] |= ((u32)(uint8_t)l0) << sh;
        w1[wd] |= ((u32)(uint8_t)l1) << sh;
        w2[wd] |= ((u32)(uint8_t)l2) << sh;
    }
    char* base = bf + (size_t)fs * 3072 + lane * 16;
    *(uint4*)(base)        = make_uint4(w0[0], w0[1], w0[2], w0[3]);
    *(uint4*)(base + 1024) = make_uint4(w1[0], w1[1], w1[2], w1[3]);
    *(uint4*)(base + 2048) = make_uint4(w2[0], w2[1], w2[2], w2[3]);
}

// ---------------- i8 MFMA GEMM: 3-limb, 8 waves x 32m, 4 waves/SIMD --------
// Grid 2048 (1D); XCD swizzle L%8 -> bm stripe. Block 512 thr = 8 waves,
// tile 256m x 32n; wave w owns m-tile g = bm*8 + w. Chunk = 256k (8 ks).
// LDS: B only, [ksl 0..7][lb 0..2] x 1KB frag-linear, dbuf (48KB). Per wave
// per chunk: 3 gload_lds; per ks: 1 A gload (prefetch) + 3 ds_read + 3 mfma.
__global__ __launch_bounds__(512, 4) void gemm_i8_3l(
    const char* __restrict__ af, const char* __restrict__ bf,
    float* __restrict__ out) {
    __shared__ __align__(16) char lds[2][24576];   // 48 KB (B only)

    const int tid  = threadIdx.x;
    const int lane = tid & 63;
    const int w    = tid >> 6;        // 0..7
    const int l31  = lane & 31;
    const int lh   = lane >> 5;

    const int L   = blockIdx.x;       // 0..2047
    const int xcd = L & 7;
    const int j   = L >> 3;           // 0..255
    const int bm  = xcd * 8 + (j & 7);  // 0..63 : XCD owns an 8-wide bm stripe
    const int bn  = j >> 3;             // 0..31

    v16i acc[3] = {};                 // [limb]

    // B panel (fragment-major, 3KB per ks): wave w stages chunk bytes
    // [w*3072, w*3072+3072) = frags (ksl, lb) with ksl*3+lb in {3w..3w+2}
    const char* gB = bf + (size_t)bn * 98304 + (size_t)w * 3072 + lane * 16;
    const int   lB = w * 3072 + lane * 16;

    // A fragment source (lane-linear): m-tile g = bm*8 + w
    const char* gA = af + (size_t)(bm * 8 + w) * 32768 + lane * 16;

    // prologue: stage B chunk 0 into buffer 0; A reg for kg 0
    #pragma unroll
    for (int q = 0; q < 3; ++q)
        gload_lds16(gB + q * 1024, (char*)lds[0] + lB + q * 1024);
    v4i aw = *(const v4i*)(gA);
    v4i an;
    __syncthreads();

    for (int c = 0; c < 4; ++c) {     // 4 chunks of 256 k
        const char* rb = lds[c & 1];
        char* wb = (char*)lds[(c & 1) ^ 1];
        if (c < 3) {
            #pragma unroll
            for (int q = 0; q < 3; ++q)
                gload_lds16(gB + (size_t)(c + 1) * 24576 + q * 1024,
                            wb + lB + q * 1024);
        }
        #pragma unroll
        for (int ksl = 0; ksl < 8; ++ksl) {
            const int kg = c * 8 + ksl;
            if (kg + 1 < 32) an = *(const v4i*)(gA + (kg + 1) * 1024);
            #pragma unroll
            for (int lb = 0; lb < 3; ++lb) {
                const v4i b = *(const v4i*)(rb + ksl * 3072 + lb * 1024 + lane * 16);
                acc[lb] = __builtin_amdgcn_mfma_i32_32x32x32_i8(aw, b, acc[lb], 0, 0, 0);
            }
            aw = an;
        }
        __syncthreads();
    }

    // epilogue: combine limbs in fp64 (exact), one f32 rounding, store
    const int n = bn * 32 + l31;
    #pragma unroll
    for (int r = 0; r < 16; ++r) {
        const double s = (double)acc[0][r] + 256.0 * (double)acc[1][r] +
                         65536.0 * (double)acc[2][r];
        const float cur = (float)(s * 7.450580596923828e-9);  // * 2^-27
        const int row = (r & 3) + 8 * (r >> 2) + 4 * lh;
        const int m = (bm * 8 + w) * 32 + row;
        out[(size_t)m * N_DIM + n] = cur;
    }
}

// ======== mid tier (round-4 proven, 4-limb exact): bit-matrix A ============
__device__ __forceinline__ v4i expand16(u32 sb) {
    v4i r;
    #pragma unroll
    for (int q = 0; q < 4; ++q) {
        const u32 x = (sb >> (4 * q)) & 0xFu;
        r[q] = (int)((x * 0x00204081u) & 0x01010101u);
    }
    return r;
}

__global__ __launch_bounds__(256) void prep_bits(const float* __restrict__ X,
                                                 u64* __restrict__ bits) {
    const int gid = blockIdx.x * 256 + threadIdx.x;
    const float x = X[gid];
    const u64 m = __ballot(x != 0.0f);
    if ((threadIdx.x & 63) == 0) bits[gid >> 6] = m;
}

__global__ __launch_bounds__(256) void prep_limbs(const float* __restrict__ W,
                                                  char* __restrict__ limbs) {
    const int gid = blockIdx.x * 256 + threadIdx.x;   // 0..2^20-1
    const double d = (double)W[gid] * 34359738368.0;
    long long k = llrint(d);
    const int8_t l0 = (int8_t)k; k = (k - l0) >> 8;
    const int8_t l1 = (int8_t)k; k = (k - l1) >> 8;
    const int8_t l2 = (int8_t)k; k = (k - l2) >> 8;
    const int8_t l3 = (int8_t)k;
    limbs[gid]                 = (char)l0;
    limbs[gid + (1 << 20)]     = (char)l1;
    limbs[gid + 2 * (1 << 20)] = (char)l2;
    limbs[gid + 3 * (1 << 20)] = (char)l3;
}

__global__ __launch_bounds__(256, 2) void gemm_i8_reg2(
    const u64* __restrict__ bits, const char* __restrict__ limbs,
    float* __restrict__ out) {
    __shared__ __align__(16) char lds[2][32768];
    const int tid  = threadIdx.x;
    const int lane = tid & 63;
    const int w    = tid >> 6;
    const int l31  = lane & 31;
    const int lh   = lane >> 5;
    const int bn   = blockIdx.x;
    const int bm   = blockIdx.y;
    v16i acc[2][4] = {};
    const char* gB[8];
    #pragma unroll
    for (int j = 0; j < 8; ++j) {
        const int id = w * 8 + j;
        const int lb = id & 3, ks32 = id >> 2;
        gB[j] = limbs + (size_t)lb * (1 << 20) +
                (size_t)(bn * 32 + l31) * 1024 + (size_t)(ks32 * 32 + lh * 16);
    }
    const int ldsbase = w * 8192 + lane * 16;
    const u64* aRow0 = bits + (size_t)(bm * 256 + w * 64 + l31) * 16;
    const u64* aRow1 = aRow0 + 32 * 16;
    u64 aw0[4], aw1[4], an0[4], an1[4];
    #pragma unroll
    for (int j = 0; j < 8; ++j) gload_lds16(gB[j], lds[0] + ldsbase + j * 1024);
    #pragma unroll
    for (int q = 0; q < 4; ++q) { aw0[q] = aRow0[q]; aw1[q] = aRow1[q]; }
    __syncthreads();
    char* rb = lds[0];
    char* wb = lds[1];
    for (int c = 0; c < 4; ++c) {
        if (c < 3) {
            #pragma unroll
            for (int j = 0; j < 8; ++j)
                gload_lds16(gB[j] + (c + 1) * 256, wb + ldsbase + j * 1024);
            #pragma unroll
            for (int q = 0; q < 4; ++q) {
                an0[q] = aRow0[(c + 1) * 4 + q];
                an1[q] = aRow1[(c + 1) * 4 + q];
            }
        }
        #pragma unroll
        for (int ks = 0; ks < 8; ++ks) {
            const int sh = (ks & 1) * 32 + lh * 16;
            const v4i a0 = expand16((u32)(aw0[ks >> 1] >> sh) & 0xffffu);
            const v4i a1 = expand16((u32)(aw1[ks >> 1] >> sh) & 0xffffu);
            #pragma unroll
            for (int lb = 0; lb < 4; ++lb) {
                const v4i b = *(const v4i*)(rb + (ks * 4 + lb) * 1024 + lane * 16);
                acc[0][lb] = __builtin_amdgcn_mfma_i32_32x32x32_i8(a0, b, acc[0][lb], 0, 0, 0);
                acc[1][lb] = __builtin_amdgcn_mfma_i32_32x32x32_i8(a1, b, acc[1][lb], 0, 0, 0);
            }
        }
        __syncthreads();
        char* t2 = rb; rb = wb; wb = t2;
        #pragma unroll
        for (int q = 0; q < 4; ++q) { aw0[q] = an0[q]; aw1[q] = an1[q]; }
    }
    const int n = bn * 32 + l31;
    #pragma unroll
    for (int i = 0; i < 2; ++i) {
        #pragma unroll
        for (int r = 0; r < 16; ++r) {
            const double s = (double)acc[i][0][r] + 256.0 * (double)acc[i][1][r] +
                             65536.0 * (double)acc[i][2][r] +
                             16777216.0 * (double)acc[i][3][r];
            const float cur = (float)(s * 2.9103830456733704e-11);
            const int row = (r & 3) + 8 * (r >> 2) + 4 * lh;
            const int m = bm * 256 + w * 64 + i * 32 + row;
            out[(size_t)m * N_DIM + n] = cur;
        }
    }
}

// ---------------- LIF scan, fp64 state, depth-16 prefetch ring -------------
__global__ __launch_bounds__(256) void lif_scan4(float* __restrict__ buf) {
    const int gid = blockIdx.x * 256 + threadIdx.x;   // 0..65535
    float c[16];
    #pragma unroll
    for (int q = 0; q < 16; ++q) c[q] = buf[(size_t)q * PLANE + gid];
    double v = 0.0;
    for (int t = 0; t < T_STEPS; t += 16) {
        #pragma unroll
        for (int q = 0; q < 16; ++q) {
            const double cd = (double)c[q];
            v = v + (cd - v) * 0.5;
            const bool s = (v >= 1.0);
            buf[(size_t)(t + q) * PLANE + gid] = s ? 1.0f : 0.0f;
            v = s ? 0.0 : v;
            const int tn = t + q + 16;
            if (tn < T_STEPS) c[q] = buf[(size_t)tn * PLANE + gid];
        }
    }
}

// ---------------- fallback: round-1 fp64 GEMM (proven) ---------------------
__global__ __launch_bounds__(256) void lif_gemm_fp64(
    const float* __restrict__ X, const float* __restrict__ W,
    float* __restrict__ out) {
    __shared__ float As[64][68];
    __shared__ float Bs[64][68];
    const int tid = threadIdx.x;
    const int bn = blockIdx.x, bm = blockIdx.y;
    const int tn4 = tid & 15, tm4 = tid >> 4;
    double acc[4][4] = {};
    const int lrow = tid >> 2, lc4 = tid & 3;
    const float* Abase = X + (size_t)(bm * 64 + lrow) * K_DIM;
    const float* Bbase = W + (size_t)(bn * 64 + lrow) * K_DIM;
    for (int k0 = 0; k0 < K_DIM; k0 += 64) {
        #pragma unroll
        for (int j = 0; j < 4; ++j) {
            const int c = lc4 + 4 * j;
            float4 a = *reinterpret_cast<const float4*>(Abase + k0 + 4 * c);
            float4 b = *reinterpret_cast<const float4*>(Bbase + k0 + 4 * c);
            As[4*c+0][lrow] = a.x; As[4*c+1][lrow] = a.y;
            As[4*c+2][lrow] = a.z; As[4*c+3][lrow] = a.w;
            Bs[4*c+0][lrow] = b.x; Bs[4*c+1][lrow] = b.y;
            Bs[4*c+2][lrow] = b.z; Bs[4*c+3][lrow] = b.w;
        }
        __syncthreads();
        #pragma unroll 8
        for (int k = 0; k < 64; ++k) {
            float4 a4 = *reinterpret_cast<const float4*>(&As[k][tm4 * 4]);
            float4 b4 = *reinterpret_cast<const float4*>(&Bs[k][tn4 * 4]);
            const double ad[4] = {(double)a4.x, (double)a4.y, (double)a4.z, (double)a4.w};
            const double bd[4] = {(double)b4.x, (double)b4.y, (double)b4.z, (double)b4.w};
            #pragma unroll
            for (int i = 0; i < 4; ++i)
                #pragma unroll
                for (int j = 0; j < 4; ++j)
                    acc[i][j] = fma(ad[i], bd[j], acc[i][j]);
        }
        __syncthreads();
    }
    #pragma unroll
    for (int i = 0; i < 4; ++i) {
        const int m = bm * 64 + tm4 * 4 + i;
        float4 o;
        o.x = (float)acc[i][0]; o.y = (float)acc[i][1];
        o.z = (float)acc[i][2]; o.w = (float)acc[i][3];
        *reinterpret_cast<float4*>(out + (size_t)m * N_DIM + bn * 64 + tn4 * 4) = o;
    }
}

extern "C" void kernel_launch(void* const* d_in, const int* in_sizes, int n_in,
                              void* d_out, int out_size, void* d_ws, size_t ws_size,
                              hipStream_t stream) {
    const float* X = (const float*)d_in[0];
    const float* W = (const float*)d_in[1];
    float* out = (float*)d_out;
    char* ws = (char*)d_ws;

    if (ws_size >= (size_t)WS_AB) {
        char* afrag = ws;
        char* bfrag = ws + AB_LIMB;
        prep_bytes_f<<<M_DIM * K_DIM / (256 * 16), 256, 0, stream>>>(X, (uint4*)afrag);
        prep_limbs_f3<<<N_DIM * K_DIM / (256 * 16), 256, 0, stream>>>(W, bfrag);
        gemm_i8_3l<<<2048, 512, 0, stream>>>(afrag, bfrag, out);
    } else if (ws_size >= (size_t)WS_MT) {
        u64* bits = (u64*)ws;
        char* limbs = ws + MT_BITS;
        prep_bits<<<M_DIM * K_DIM / 256, 256, 0, stream>>>(X, bits);
        prep_limbs<<<N_DIM * K_DIM / 256, 256, 0, stream>>>(W, limbs);
        dim3 grid(N_DIM / 32, M_DIM / 256);
        gemm_i8_reg2<<<grid, 256, 0, stream>>>(bits, limbs, out);
    } else {
        dim3 grid(N_DIM / 64, M_DIM / 64);
        lif_gemm_fp64<<<grid, 256, 0, stream>>>(X, W, out);
        lif_scan4<<<PLANE / 256, 256, 0, stream>>>(out);
        return;
    }
    lif_scan4<<<PLANE / 256, 256, 0, stream>>>(out);
}

// Round 13
// 89.181 us; speedup vs baseline: 1.1299x; 1.0405x over previous
//
#include <hip/hip_runtime.h>
#include <stdint.h>

// LIF SNN: cur = X @ W^T then LIF scan. T=256,B=64,F=1024 -> M=16384,N=K=1024.
// Integer GEMM on i8 MFMA, 3 limbs at scale 2^-27 (proven absmax 0.0 in r12;
// per-dot quantization error ~5e-8 << inferred >=1e-6 decision margins).
// i32 mfma acc exact; fp64 limb combine exact; one f32 rounding.
//
// Round 13: B-REUSE x2. r12 analysis: matrix-busy (21.8us) == mfma floor
// (23.4us); wall 59us is the 1:1 ds_read:mfma LDS stream + its latency.
// Wave now owns TWO m-tiles (64m x 32n x 3 limbs, acc 96 AGPR): each B frag
// read feeds 2 mfmas -> ds:mfma = 0.5 (LDS floor ~15us < matrix floor).
// 256-thr / 4-wave blocks, __launch_bounds__(256,3) -> 3 blocks/CU (12
// waves/CU, desynced barriers). Chunk 256k, 48KB dbuf (3x48=144<160KB/CU).

#define T_STEPS 256
#define M_DIM 16384
#define N_DIM 1024
#define K_DIM 1024
#define PLANE 65536   // B*F

typedef int v4i  __attribute__((ext_vector_type(4)));
typedef int v16i __attribute__((ext_vector_type(16)));
typedef unsigned int u32;
typedef unsigned long long u64;

// ws layouts
#define AB_BYTES   (M_DIM * K_DIM)                  // 16 MB A fragment bytes
#define AB_LIMB    AB_BYTES                         // B fragments at +16MB (3MB)
#define WS_AB      (AB_BYTES + 4 * (1 << 20))       // 20 MB budget
#define MT_BITS    (M_DIM * 128)                    // 2 MB bit matrix
#define WS_MT      (MT_BITS + 4 * (1 << 20))        // 6 MB (mid tier, 4-limb)

__device__ __forceinline__ void gload_lds16(const void* g, void* l) {
    __builtin_amdgcn_global_load_lds(
        (const __attribute__((address_space(1))) u32*)g,
        (__attribute__((address_space(3))) u32*)l, 16, 0, 0);
}

// ------- prep: X (0/1 f32) -> A fragments [g 0..511][ks 0..31][lane][16B] ---
__global__ __launch_bounds__(256) void prep_bytes_f(const float* __restrict__ X,
                                                    uint4* __restrict__ af) {
    const int gid  = blockIdx.x * 256 + threadIdx.x;  // 0..1048575
    const int lane = gid & 63;
    const int fs   = gid >> 6;                        // g*32 + ks
    const int m    = (fs >> 5) * 32 + (lane & 31);
    const int k    = (fs & 31) * 32 + (lane >> 5) * 16;
    const float4* src = reinterpret_cast<const float4*>(X + (size_t)m * K_DIM + k);
    uint4 r;
    u32* pr = &r.x;
    #pragma unroll
    for (int q = 0; q < 4; ++q) {
        const float4 f = src[q];
        pr[q] = (f.x != 0.f ? 1u : 0u) | (f.y != 0.f ? 0x100u : 0u) |
                (f.z != 0.f ? 0x10000u : 0u) | (f.w != 0.f ? 0x1000000u : 0u);
    }
    af[gid] = r;
}

// ---- prep: W -> B 3-limb fragments [c 0..31][ks 0..31][lb 0..2][lane][16B] -
__global__ __launch_bounds__(256) void prep_limbs_f3(const float* __restrict__ W,
                                                     char* __restrict__ bf) {
    const int gid  = blockIdx.x * 256 + threadIdx.x;  // 0..65535
    const int lane = gid & 63;
    const int fs   = gid >> 6;                        // c*32 + ks
    const int n    = (fs >> 5) * 32 + (lane & 31);
    const int k    = (fs & 31) * 32 + (lane >> 5) * 16;
    const float* src = W + (size_t)n * K_DIM + k;
    u32 w0[4] = {}, w1[4] = {}, w2[4] = {};
    #pragma unroll
    for (int e = 0; e < 16; ++e) {
        const double d = (double)src[e] * 134217728.0;    // * 2^27, exact
        long long kq = llrint(d);                         // |kq| <= 2^22
        const int8_t l0 = (int8_t)kq; kq = (kq - l0) >> 8;  // balanced digits
        const int8_t l1 = (int8_t)kq; kq = (kq - l1) >> 8;
        const int8_t l2 = (int8_t)kq;                     // |l2| <= 64
        const int sh = (e & 3) * 8, wd = e >> 2;
        w0[wd] |= ((u32)(uint8_t)l0) << sh;
        w1[wd] |= ((u32)(uint8_t)l1) << sh;
        w2[wd] |= ((u32)(uint8_t)l2) << sh;
    }
    char* base = bf + (size_t)fs * 3072 + lane * 16;
    *(uint4*)(base)        = make_uint4(w0[0], w0[1], w0[2], w0[3]);
    *(uint4*)(base + 1024) = make_uint4(w1[0], w1[1], w1[2], w1[3]);
    *(uint4*)(base + 2048) = make_uint4(w2[0], w2[1], w2[2], w2[3]);
}

// ------- i8 MFMA GEMM: 3-limb, B-reuse x2, 4-wave blocks, 3 blocks/CU ------
// Grid 2048 (1D); XCD swizzle L%8 -> bm stripe. Block 256 thr = 4 waves,
// tile 256m x 32n; wave w owns m-tiles g = bm*8 + 2w, +1. Chunk = 256k
// (8 ks). LDS: B only, [ksl 0..7][lb 0..2] x 1KB frag-linear, dbuf 48KB.
// Per wave per chunk: 6 gload_lds; per ks: 2 A gloads + 3 ds_read + 6 mfma.
__global__ __launch_bounds__(256, 3) void gemm_i8_3l2(
    const char* __restrict__ af, const char* __restrict__ bf,
    float* __restrict__ out) {
    __shared__ __align__(16) char lds[2][24576];   // 48 KB (B only)

    const int tid  = threadIdx.x;
    const int lane = tid & 63;
    const int w    = tid >> 6;        // 0..3
    const int l31  = lane & 31;
    const int lh   = lane >> 5;

    const int L   = blockIdx.x;       // 0..2047
    const int xcd = L & 7;
    const int j   = L >> 3;           // 0..255
    const int bm  = xcd * 8 + (j & 7);  // 0..63 : XCD owns an 8-wide bm stripe
    const int bn  = j >> 3;             // 0..31

    v16i acc[2][3] = {};              // [m-tile][limb]

    // B panel (fragment-major, 3KB/ks): wave w stages frag ids 6w..6w+5
    // (id = ksl*3 + lb), i.e. chunk bytes [w*6144, w*6144+6144), lane-linear.
    const char* gB = bf + (size_t)bn * 98304 + (size_t)w * 6144 + lane * 16;
    const int   lB = w * 6144 + lane * 16;

    // A fragment sources (lane-linear): m-tiles g = bm*8 + 2w, +1
    const char* gA0 = af + (size_t)(bm * 8 + 2 * w) * 32768 + lane * 16;
    const char* gA1 = gA0 + 32768;

    // prologue: stage B chunk 0 into buffer 0; A regs for kg 0
    #pragma unroll
    for (int q = 0; q < 6; ++q)
        gload_lds16(gB + q * 1024, (char*)lds[0] + lB + q * 1024);
    v4i aw0 = *(const v4i*)(gA0);
    v4i aw1 = *(const v4i*)(gA1);
    v4i an0, an1;
    __syncthreads();

    for (int c = 0; c < 4; ++c) {     // 4 chunks of 256 k
        const char* rb = lds[c & 1];
        char* wb = (char*)lds[(c & 1) ^ 1];
        if (c < 3) {
            #pragma unroll
            for (int q = 0; q < 6; ++q)
                gload_lds16(gB + (size_t)(c + 1) * 24576 + q * 1024,
                            wb + lB + q * 1024);
        }
        #pragma unroll
        for (int ksl = 0; ksl < 8; ++ksl) {
            const int kg = c * 8 + ksl;
            if (kg + 1 < 32) {
                an0 = *(const v4i*)(gA0 + (kg + 1) * 1024);
                an1 = *(const v4i*)(gA1 + (kg + 1) * 1024);
            }
            #pragma unroll
            for (int lb = 0; lb < 3; ++lb) {
                const v4i b = *(const v4i*)(rb + ksl * 3072 + lb * 1024 + lane * 16);
                acc[0][lb] = __builtin_amdgcn_mfma_i32_32x32x32_i8(aw0, b, acc[0][lb], 0, 0, 0);
                acc[1][lb] = __builtin_amdgcn_mfma_i32_32x32x32_i8(aw1, b, acc[1][lb], 0, 0, 0);
            }
            aw0 = an0; aw1 = an1;
        }
        __syncthreads();
    }

    // epilogue: combine limbs in fp64 (exact), one f32 rounding, store
    const int n = bn * 32 + l31;
    #pragma unroll
    for (int i = 0; i < 2; ++i) {
        #pragma unroll
        for (int r = 0; r < 16; ++r) {
            const double s = (double)acc[i][0][r] + 256.0 * (double)acc[i][1][r] +
                             65536.0 * (double)acc[i][2][r];
            const float cur = (float)(s * 7.450580596923828e-9);  // * 2^-27
            const int row = (r & 3) + 8 * (r >> 2) + 4 * lh;
            const int m = (bm * 8 + 2 * w + i) * 32 + row;
            out[(size_t)m * N_DIM + n] = cur;
        }
    }
}

// ======== mid tier (round-4 proven, 4-limb exact): bit-matrix A ============
__device__ __forceinline__ v4i expand16(u32 sb) {
    v4i r;
    #pragma unroll
    for (int q = 0; q < 4; ++q) {
        const u32 x = (sb >> (4 * q)) & 0xFu;
        r[q] = (int)((x * 0x00204081u) & 0x01010101u);
    }
    return r;
}

__global__ __launch_bounds__(256) void prep_bits(const float* __restrict__ X,
                                                 u64* __restrict__ bits) {
    const int gid = blockIdx.x * 256 + threadIdx.x;
    const float x = X[gid];
    const u64 m = __ballot(x != 0.0f);
    if ((threadIdx.x & 63) == 0) bits[gid >> 6] = m;
}

__global__ __launch_bounds__(256) void prep_limbs(const float* __restrict__ W,
                                                  char* __restrict__ limbs) {
    const int gid = blockIdx.x * 256 + threadIdx.x;   // 0..2^20-1
    const double d = (double)W[gid] * 34359738368.0;
    long long k = llrint(d);
    const int8_t l0 = (int8_t)k; k = (k - l0) >> 8;
    const int8_t l1 = (int8_t)k; k = (k - l1) >> 8;
    const int8_t l2 = (int8_t)k; k = (k - l2) >> 8;
    const int8_t l3 = (int8_t)k;
    limbs[gid]                 = (char)l0;
    limbs[gid + (1 << 20)]     = (char)l1;
    limbs[gid + 2 * (1 << 20)] = (char)l2;
    limbs[gid + 3 * (1 << 20)] = (char)l3;
}

__global__ __launch_bounds__(256, 2) void gemm_i8_reg2(
    const u64* __restrict__ bits, const char* __restrict__ limbs,
    float* __restrict__ out) {
    __shared__ __align__(16) char lds[2][32768];
    const int tid  = threadIdx.x;
    const int lane = tid & 63;
    const int w    = tid >> 6;
    const int l31  = lane & 31;
    const int lh   = lane >> 5;
    const int bn   = blockIdx.x;
    const int bm   = blockIdx.y;
    v16i acc[2][4] = {};
    const char* gB[8];
    #pragma unroll
    for (int j = 0; j < 8; ++j) {
        const int id = w * 8 + j;
        const int lb = id & 3, ks32 = id >> 2;
        gB[j] = limbs + (size_t)lb * (1 << 20) +
                (size_t)(bn * 32 + l31) * 1024 + (size_t)(ks32 * 32 + lh * 16);
    }
    const int ldsbase = w * 8192 + lane * 16;
    const u64* aRow0 = bits + (size_t)(bm * 256 + w * 64 + l31) * 16;
    const u64* aRow1 = aRow0 + 32 * 16;
    u64 aw0[4], aw1[4], an0[4], an1[4];
    #pragma unroll
    for (int j = 0; j < 8; ++j) gload_lds16(gB[j], lds[0] + ldsbase + j * 1024);
    #pragma unroll
    for (int q = 0; q < 4; ++q) { aw0[q] = aRow0[q]; aw1[q] = aRow1[q]; }
    __syncthreads();
    char* rb = lds[0];
    char* wb = lds[1];
    for (int c = 0; c < 4; ++c) {
        if (c < 3) {
            #pragma unroll
            for (int j = 0; j < 8; ++j)
                gload_lds16(gB[j] + (c + 1) * 256, wb + ldsbase + j * 1024);
            #pragma unroll
            for (int q = 0; q < 4; ++q) {
                an0[q] = aRow0[(c + 1) * 4 + q];
                an1[q] = aRow1[(c + 1) * 4 + q];
            }
        }
        #pragma unroll
        for (int ks = 0; ks < 8; ++ks) {
            const int sh = (ks & 1) * 32 + lh * 16;
            const v4i a0 = expand16((u32)(aw0[ks >> 1] >> sh) & 0xffffu);
            const v4i a1 = expand16((u32)(aw1[ks >> 1] >> sh) & 0xffffu);
            #pragma unroll
            for (int lb = 0; lb < 4; ++lb) {
                const v4i b = *(const v4i*)(rb + (ks * 4 + lb) * 1024 + lane * 16);
                acc[0][lb] = __builtin_amdgcn_mfma_i32_32x32x32_i8(a0, b, acc[0][lb], 0, 0, 0);
                acc[1][lb] = __builtin_amdgcn_mfma_i32_32x32x32_i8(a1, b, acc[1][lb], 0, 0, 0);
            }
        }
        __syncthreads();
        char* t2 = rb; rb = wb; wb = t2;
        #pragma unroll
        for (int q = 0; q < 4; ++q) { aw0[q] = an0[q]; aw1[q] = an1[q]; }
    }
    const int n = bn * 32 + l31;
    #pragma unroll
    for (int i = 0; i < 2; ++i) {
        #pragma unroll
        for (int r = 0; r < 16; ++r) {
            const double s = (double)acc[i][0][r] + 256.0 * (double)acc[i][1][r] +
                             65536.0 * (double)acc[i][2][r] +
                             16777216.0 * (double)acc[i][3][r];
            const float cur = (float)(s * 2.9103830456733704e-11);
            const int row = (r & 3) + 8 * (r >> 2) + 4 * lh;
            const int m = bm * 256 + w * 64 + i * 32 + row;
            out[(size_t)m * N_DIM + n] = cur;
        }
    }
}

// ---------------- LIF scan, fp64 state, depth-16 prefetch ring -------------
__global__ __launch_bounds__(256) void lif_scan4(float* __restrict__ buf) {
    const int gid = blockIdx.x * 256 + threadIdx.x;   // 0..65535
    float c[16];
    #pragma unroll
    for (int q = 0; q < 16; ++q) c[q] = buf[(size_t)q * PLANE + gid];
    double v = 0.0;
    for (int t = 0; t < T_STEPS; t += 16) {
        #pragma unroll
        for (int q = 0; q < 16; ++q) {
            const double cd = (double)c[q];
            v = v + (cd - v) * 0.5;
            const bool s = (v >= 1.0);
            buf[(size_t)(t + q) * PLANE + gid] = s ? 1.0f : 0.0f;
            v = s ? 0.0 : v;
            const int tn = t + q + 16;
            if (tn < T_STEPS) c[q] = buf[(size_t)tn * PLANE + gid];
        }
    }
}

// ---------------- fallback: round-1 fp64 GEMM (proven) ---------------------
__global__ __launch_bounds__(256) void lif_gemm_fp64(
    const float* __restrict__ X, const float* __restrict__ W,
    float* __restrict__ out) {
    __shared__ float As[64][68];
    __shared__ float Bs[64][68];
    const int tid = threadIdx.x;
    const int bn = blockIdx.x, bm = blockIdx.y;
    const int tn4 = tid & 15, tm4 = tid >> 4;
    double acc[4][4] = {};
    const int lrow = tid >> 2, lc4 = tid & 3;
    const float* Abase = X + (size_t)(bm * 64 + lrow) * K_DIM;
    const float* Bbase = W + (size_t)(bn * 64 + lrow) * K_DIM;
    for (int k0 = 0; k0 < K_DIM; k0 += 64) {
        #pragma unroll
        for (int j = 0; j < 4; ++j) {
            const int c = lc4 + 4 * j;
            float4 a = *reinterpret_cast<const float4*>(Abase + k0 + 4 * c);
            float4 b = *reinterpret_cast<const float4*>(Bbase + k0 + 4 * c);
            As[4*c+0][lrow] = a.x; As[4*c+1][lrow] = a.y;
            As[4*c+2][lrow] = a.z; As[4*c+3][lrow] = a.w;
            Bs[4*c+0][lrow] = b.x; Bs[4*c+1][lrow] = b.y;
            Bs[4*c+2][lrow] = b.z; Bs[4*c+3][lrow] = b.w;
        }
        __syncthreads();
        #pragma unroll 8
        for (int k = 0; k < 64; ++k) {
            float4 a4 = *reinterpret_cast<const float4*>(&As[k][tm4 * 4]);
            float4 b4 = *reinterpret_cast<const float4*>(&Bs[k][tn4 * 4]);
            const double ad[4] = {(double)a4.x, (double)a4.y, (double)a4.z, (double)a4.w};
            const double bd[4] = {(double)b4.x, (double)b4.y, (double)b4.z, (double)b4.w};
            #pragma unroll
            for (int i = 0; i < 4; ++i)
                #pragma unroll
                for (int j = 0; j < 4; ++j)
                    acc[i][j] = fma(ad[i], bd[j], acc[i][j]);
        }
        __syncthreads();
    }
    #pragma unroll
    for (int i = 0; i < 4; ++i) {
        const int m = bm * 64 + tm4 * 4 + i;
        float4 o;
        o.x = (float)acc[i][0]; o.y = (float)acc[i][1];
        o.z = (float)acc[i][2]; o.w = (float)acc[i][3];
        *reinterpret_cast<float4*>(out + (size_t)m * N_DIM + bn * 64 + tn4 * 4) = o;
    }
}

extern "C" void kernel_launch(void* const* d_in, const int* in_sizes, int n_in,
                              void* d_out, int out_size, void* d_ws, size_t ws_size,
                              hipStream_t stream) {
    const float* X = (const float*)d_in[0];
    const float* W = (const float*)d_in[1];
    float* out = (float*)d_out;
    char* ws = (char*)d_ws;

    if (ws_size >= (size_t)WS_AB) {
        char* afrag = ws;
        char* bfrag = ws + AB_LIMB;
        prep_bytes_f<<<M_DIM * K_DIM / (256 * 16), 256, 0, stream>>>(X, (uint4*)afrag);
        prep_limbs_f3<<<N_DIM * K_DIM / (256 * 16), 256, 0, stream>>>(W, bfrag);
        gemm_i8_3l2<<<2048, 256, 0, stream>>>(afrag, bfrag, out);
    } else if (ws_size >= (size_t)WS_MT) {
        u64* bits = (u64*)ws;
        char* limbs = ws + MT_BITS;
        prep_bits<<<M_DIM * K_DIM / 256, 256, 0, stream>>>(X, bits);
        prep_limbs<<<N_DIM * K_DIM / 256, 256, 0, stream>>>(W, limbs);
        dim3 grid(N_DIM / 32, M_DIM / 256);
        gemm_i8_reg2<<<grid, 256, 0, stream>>>(bits, limbs, out);
    } else {
        dim3 grid(N_DIM / 64, M_DIM / 64);
        lif_gemm_fp64<<<grid, 256, 0, stream>>>(X, W, out);
        lif_scan4<<<PLANE / 256, 256, 0, stream>>>(out);
        return;
    }
    lif_scan4<<<PLANE / 256, 256, 0, stream>>>(out);
}